// Round 1
// baseline (432.107 us; speedup 1.0000x reference)
//
#include <hip/hip_runtime.h>
#include <math.h>

#define NEG_INF (-INFINITY)

// out0[i][j] = max(c0[i][j], c1[i][j], c0[i+1][j], c0[i][j+1], c0[i+1][j+1])
// out1[i][j] = max(c1[i][j], c1[i+1][j], c1[i][j+1], c1[i+1][j+1], c0[i+1][j+1])
// One thread computes 4 contiguous j for BOTH outputs (shared loads).
__global__ __launch_bounds__(256) void quincunx_pool_kernel(
    const float* __restrict__ c0, const float* __restrict__ c1,
    float* __restrict__ out, long N /* elems per coset */)
{
    const int H = 512, W = 512;
    const int wq = W >> 2;  // 128 column-groups per row

    long idx = (long)blockIdx.x * blockDim.x + threadIdx.x;
    int j4 = (int)(idx % wq) * 4;
    int i  = (int)((idx / wq) % H);
    long p = idx / ((long)wq * H);

    long base = p * (long)(H * W) + (long)i * W + j4;

    // Row i of both cosets (always in range).
    float4 a0 = *(const float4*)(c0 + base);
    float4 b0 = *(const float4*)(c1 + base);

    // Row i+1, -inf padded at the bottom edge.
    const bool hasI1 = (i + 1) < H;
    float4 a1, b1;
    if (hasI1) {
        a1 = *(const float4*)(c0 + base + W);
        b1 = *(const float4*)(c1 + base + W);
    } else {
        a1 = make_float4(NEG_INF, NEG_INF, NEG_INF, NEG_INF);
        b1 = a1;
    }

    // j+1 spill-over element at j4+4 (only needed for lane 3 of the vector).
    const bool hasJ = (j4 + 4) < W;
    float a0e = hasJ ? c0[base + 4] : NEG_INF;
    float b0e = hasJ ? c1[base + 4] : NEG_INF;
    float a1e = (hasJ && hasI1) ? c0[base + W + 4] : NEG_INF;
    float b1e = (hasJ && hasI1) ? c1[base + W + 4] : NEG_INF;

    float4 o0, o1;
    // element 0 (j = j4):  j+1 values are the .y components
    o0.x = fmaxf(fmaxf(fmaxf(a0.x, b0.x), fmaxf(a1.x, a0.y)), a1.y);
    o1.x = fmaxf(fmaxf(fmaxf(b0.x, b1.x), fmaxf(b0.y, b1.y)), a1.y);
    // element 1
    o0.y = fmaxf(fmaxf(fmaxf(a0.y, b0.y), fmaxf(a1.y, a0.z)), a1.z);
    o1.y = fmaxf(fmaxf(fmaxf(b0.y, b1.y), fmaxf(b0.z, b1.z)), a1.z);
    // element 2
    o0.z = fmaxf(fmaxf(fmaxf(a0.z, b0.z), fmaxf(a1.z, a0.w)), a1.w);
    o1.z = fmaxf(fmaxf(fmaxf(b0.z, b1.z), fmaxf(b0.w, b1.w)), a1.w);
    // element 3: j+1 values come from the edge loads
    o0.w = fmaxf(fmaxf(fmaxf(a0.w, b0.w), fmaxf(a1.w, a0e)), a1e);
    o1.w = fmaxf(fmaxf(fmaxf(b0.w, b1.w), fmaxf(b0e, b1e)), a1e);

    *(float4*)(out + base)     = o0;
    *(float4*)(out + N + base) = o1;
}

extern "C" void kernel_launch(void* const* d_in, const int* in_sizes, int n_in,
                              void* d_out, int out_size, void* d_ws, size_t ws_size,
                              hipStream_t stream) {
    const float* c0 = (const float*)d_in[0];
    const float* c1 = (const float*)d_in[1];
    float* out = (float*)d_out;

    const int H = 512, W = 512;
    long N = (long)in_sizes[0];              // elements per coset = 4*32*512*512
    long total_threads = N / 4;              // one thread per 4 columns
    int threads = 256;
    int blocks = (int)((total_threads + threads - 1) / threads);

    quincunx_pool_kernel<<<blocks, threads, 0, stream>>>(c0, c1, out, N);
}